// Round 1
// baseline (650.144 us; speedup 1.0000x reference)
//
#include <hip/hip_runtime.h>

// LocallyConnected2d: B=32, C_IN=64, H=W=56, C_OUT=64, K=3x3, pad=1, stride=1
// out[b,c,l] = sum_f patches[b,l,f] * weight[l,c,f] + bias[l,c]
// f = cin*9 + ki*3 + kj  (channel-major unfold)
//
// Strategy: weight (462 MB fp32) is the dominant, read-once stream -> HBM-bound
// floor ~82 us. Compute via bf16 MFMA (16x16x32) so matrix math is negligible.
// x is pre-transposed into T[58][58][b][cin] bf16 (halo-padded) in d_ws so the
// per-location patch gather becomes 9 contiguous 4KB slab reads.

#define BATCH   32
#define CIN     64
#define HWDIM   56
#define COUT    64
#define NLOC    3136
#define FEAT    576
#define TPAD    58
#define SLAB    2048      // 32*64 bf16 elems per (ip,jp)
#define ROWLEN  584       // 576 + 8 pad (keeps 16B row alignment, breaks pow2 stride)

typedef __attribute__((ext_vector_type(8))) short short8;
typedef __attribute__((ext_vector_type(4))) float f32x4;

__device__ __forceinline__ unsigned short f2bf(float f) {
    union { float f; unsigned u; } cv; cv.f = f;
    // round-to-nearest-even bf16
    return (unsigned short)((cv.u + 0x7fffu + ((cv.u >> 16) & 1u)) >> 16);
}

// ---------------------------------------------------------------------------
// x [32][64][56][56] f32  ->  T [58][58][32][64] bf16 (zero halo, pad=1)
// Tiled transpose: coalesced float4 reads along w, 16B bf16 packed writes
// along the cin-contiguous output dim.
// ---------------------------------------------------------------------------
__global__ __launch_bounds__(256) void xform_kernel(const float* __restrict__ x,
                                                    unsigned short* __restrict__ T) {
    __shared__ float tile[64][65];       // +1 pad: conflict-free column reads
    const int b   = blockIdx.y;
    const int hw0 = blockIdx.x * 64;     // 3136 = 49 * 64 exactly
    const int t   = threadIdx.x;
    const float* xb = x + (size_t)b * CIN * (HWDIM * HWDIM);

    const int cl = t >> 4;               // 0..15
    const int wl = (t & 15) * 4;         // 0..60
#pragma unroll
    for (int rr = 0; rr < 4; ++rr) {
        const int cin = cl + rr * 16;
        const float4 v = *(const float4*)(xb + (size_t)cin * (HWDIM * HWDIM) + hw0 + wl);
        tile[cin][wl]     = v.x;
        tile[cin][wl + 1] = v.y;
        tile[cin][wl + 2] = v.z;
        tile[cin][wl + 3] = v.w;
    }
    __syncthreads();

    const int hwl = t >> 2;              // 0..63
    const int c0  = (t & 3) * 16;        // 0,16,32,48
    const int hw  = hw0 + hwl;
    const int i   = hw / HWDIM;
    const int j   = hw % HWDIM;
    short8 o0, o1;
#pragma unroll
    for (int k = 0; k < 8; ++k) {
        o0[k] = (short)f2bf(tile[c0 + k][hwl]);
        o1[k] = (short)f2bf(tile[c0 + 8 + k][hwl]);
    }
    unsigned short* dst = T + ((size_t)(i + 1) * TPAD + (j + 1)) * SLAB + b * 64 + c0;
    *(short8*)dst       = o0;
    *(short8*)(dst + 8) = o1;
}

// ---------------------------------------------------------------------------
// Main kernel: one block per location l. 256 threads = 4 waves.
// Phase 1: gather 9 slabs (contiguous 4KB each) -> LDS sA[b][f] bf16.
// Phase 2: m97-style "gemm_bt": W[l,c,f] rows ARE the MFMA B-operand rows
// (B^T layout, k contiguous). Each wave: N-tile = wave id (16 cols),
// both M-tiles (32 rows), K = 576 in 18 steps of 32.
// ---------------------------------------------------------------------------
__global__ __launch_bounds__(256, 4) void lc2d_kernel(
    const unsigned short* __restrict__ T,   // [58][58][32][64] bf16
    const float* __restrict__ W,            // [NLOC][64][576] f32
    const float* __restrict__ bias,         // [NLOC][64] f32
    float* __restrict__ out)                // [32][64][3136] f32
{
    __shared__ unsigned short sA[BATCH][ROWLEN];   // 37,376 B -> 4 blocks/CU

    const int bid = blockIdx.x;
    // XCD-contiguous l ranges: consecutive l share T slabs + out cache lines.
    const int l  = (bid & 7) * (NLOC / 8) + (bid >> 3);
    const int oi = l / HWDIM;
    const int oj = l % HWDIM;
    const int t  = threadIdx.x;

    // ---- Phase 1: patches -> LDS --------------------------------------
    {
        const int b  = t >> 3;           // 0..31
        const int c0 = (t & 7) * 8;      // cin chunk base: 0,8,..,56
        short8 ld[9];
#pragma unroll
        for (int ki = 0; ki < 3; ++ki)
#pragma unroll
            for (int kj = 0; kj < 3; ++kj) {
                const unsigned short* src =
                    T + ((size_t)(oi + ki) * TPAD + (oj + kj)) * SLAB + b * 64 + c0;
                ld[ki * 3 + kj] = *(const short8*)src;
            }
        // repack: f = (c0+ci)*9 + k  -> 72 contiguous bf16 = 9 x b128 stores
        short8 ov[9];
#pragma unroll
        for (int ci = 0; ci < 8; ++ci)
#pragma unroll
            for (int k = 0; k < 9; ++k) {
                const int o = ci * 9 + k;
                ov[o >> 3][o & 7] = ld[k][ci];
            }
        short8* dst = (short8*)&sA[b][c0 * 9];
#pragma unroll
        for (int w = 0; w < 9; ++w) dst[w] = ov[w];
    }
    __syncthreads();

    // ---- Phase 2: stream W, MFMA --------------------------------------
    const int ln = t & 63;
    const int wv = t >> 6;               // wave id = N-tile
    const int r  = ln & 15;              // row within operand (m or n)
    const int q  = ln >> 4;              // quad: k-offset q*8

    const float* wrow = W + (size_t)l * (COUT * FEAT)
                          + (size_t)(wv * 16 + r) * FEAT + q * 8;
    const unsigned short* a0 = &sA[r][q * 8];        // M-tile 0
    const unsigned short* a1 = &sA[16 + r][q * 8];   // M-tile 1

    f32x4 acc0 = {0.f, 0.f, 0.f, 0.f};
    f32x4 acc1 = {0.f, 0.f, 0.f, 0.f};

    float4 w0 = *(const float4*)(wrow);
    float4 w1 = *(const float4*)(wrow + 4);
#pragma unroll 2
    for (int kk = 0; kk < 18; ++kk) {
        float4 nw0, nw1;
        if (kk < 17) {                   // register-rotated prefetch
            nw0 = *(const float4*)(wrow + (kk + 1) * 32);
            nw1 = *(const float4*)(wrow + (kk + 1) * 32 + 4);
        }
        short8 bfrag;
        bfrag[0] = (short)f2bf(w0.x);
        bfrag[1] = (short)f2bf(w0.y);
        bfrag[2] = (short)f2bf(w0.z);
        bfrag[3] = (short)f2bf(w0.w);
        bfrag[4] = (short)f2bf(w1.x);
        bfrag[5] = (short)f2bf(w1.y);
        bfrag[6] = (short)f2bf(w1.z);
        bfrag[7] = (short)f2bf(w1.w);
        const short8 af0 = *(const short8*)(a0 + kk * 32);
        const short8 af1 = *(const short8*)(a1 + kk * 32);
        acc0 = __builtin_amdgcn_mfma_f32_16x16x32_bf16(af0, bfrag, acc0, 0, 0, 0);
        acc1 = __builtin_amdgcn_mfma_f32_16x16x32_bf16(af1, bfrag, acc1, 0, 0, 0);
        w0 = nw0;
        w1 = nw1;
    }

    // ---- Epilogue: C/D layout col(n=c)=lane&15, row(m=b)=q*4+reg ------
    const int c   = wv * 16 + r;
    const float bv = bias[l * COUT + c];
    float* op = out + (size_t)c * NLOC + l;
#pragma unroll
    for (int i2 = 0; i2 < 4; ++i2) {
        const int b0 = q * 4 + i2;
        op[(size_t)b0 * (COUT * NLOC)]        = acc0[i2] + bv;
        op[(size_t)(b0 + 16) * (COUT * NLOC)] = acc1[i2] + bv;
    }
}

extern "C" void kernel_launch(void* const* d_in, const int* in_sizes, int n_in,
                              void* d_out, int out_size, void* d_ws, size_t ws_size,
                              hipStream_t stream) {
    const float* x    = (const float*)d_in[0];
    const float* w    = (const float*)d_in[1];
    const float* bias = (const float*)d_in[2];
    float* out        = (float*)d_out;

    unsigned short* T = (unsigned short*)d_ws;
    const size_t tbytes = (size_t)TPAD * TPAD * SLAB * sizeof(unsigned short); // ~13.8 MB

    hipMemsetAsync(d_ws, 0, tbytes, stream);                     // zero halo
    xform_kernel<<<dim3(49, 32), 256, 0, stream>>>(x, T);
    lc2d_kernel<<<dim3(NLOC), 256, 0, stream>>>(T, w, bias, out);
}

// Round 3
// 643.635 us; speedup vs baseline: 1.0101x; 1.0101x over previous
//
#include <hip/hip_runtime.h>

// LocallyConnected2d: B=32, C_IN=64, H=W=56, C_OUT=64, K=3x3, pad=1, stride=1
// out[b,c,l] = sum_f patches[b,l,f] * weight[l,c,f] + bias[l,c]
// f = cin*9 + ki*3 + kj  (channel-major unfold)
//
// Weight (462 MB fp32) is the dominant read-once stream -> HBM-bound floor
// ~75 us. Compute via bf16 MFMA (16x16x32). x is pre-transposed into
// T[58][58][b][cin] bf16 (halo zeroed in-kernel) so the per-location patch
// gather becomes 9 contiguous 4KB slab reads. W loads are non-temporal so the
// 462 MB stream doesn't evict T (re-read 9x) / out lines from L2.

#define BATCH   32
#define CIN     64
#define HWDIM   56
#define COUT    64
#define NLOC    3136
#define FEAT    576
#define TPAD    58
#define SLAB    2048      // 32*64 bf16 elems per (ip,jp)
#define ROWLEN  584       // 576 + 8 pad (16B-aligned rows, breaks pow2 stride)

typedef __attribute__((ext_vector_type(8))) short short8;
typedef __attribute__((ext_vector_type(4))) float f32x4;   // native vec: ok for nontemporal builtins

__device__ __forceinline__ unsigned short f2bf(float f) {
    union { float f; unsigned u; } cv; cv.f = f;
    return (unsigned short)((cv.u + 0x7fffu + ((cv.u >> 16) & 1u)) >> 16);  // RNE
}

// ---------------------------------------------------------------------------
// x [32][64][56][56] f32  ->  T [58][58][32][64] bf16 (zero halo, pad=1)
// grid (50, 32): bx<49 transpose 64 hw-positions; bx==49 zeroes halo slabs.
// ---------------------------------------------------------------------------
__global__ __launch_bounds__(256) void xform_kernel(const float* __restrict__ x,
                                                    unsigned short* __restrict__ T) {
    const int t = threadIdx.x;

    if (blockIdx.x == 49) {
        // zero the 228 halo slabs (rows 0 & 57, cols 0 & 57)
        const short8 z = {0, 0, 0, 0, 0, 0, 0, 0};
        for (int s = blockIdx.y; s < 228; s += 32) {
            int ip, jp;
            if (s < 58)       { ip = 0;        jp = s; }
            else if (s < 116) { ip = 57;       jp = s - 58; }
            else if (s < 172) { ip = s - 115;  jp = 0; }       // rows 1..56
            else              { ip = s - 171;  jp = 57; }      // rows 1..56
            unsigned short* dst = T + ((size_t)ip * TPAD + jp) * SLAB + t * 8;
            *(short8*)dst = z;
        }
        return;
    }

    __shared__ float tile[64][65];       // +1 pad: conflict-free column reads
    const int b   = blockIdx.y;
    const int hw0 = blockIdx.x * 64;     // 3136 = 49 * 64 exactly
    const float* xb = x + (size_t)b * CIN * (HWDIM * HWDIM);

    const int cl = t >> 4;               // 0..15
    const int wl = (t & 15) * 4;         // 0..60
#pragma unroll
    for (int rr = 0; rr < 4; ++rr) {
        const int cin = cl + rr * 16;
        const float4 v = *(const float4*)(xb + (size_t)cin * (HWDIM * HWDIM) + hw0 + wl);
        tile[cin][wl]     = v.x;
        tile[cin][wl + 1] = v.y;
        tile[cin][wl + 2] = v.z;
        tile[cin][wl + 3] = v.w;
    }
    __syncthreads();

    const int hwl = t >> 2;              // 0..63
    const int c0  = (t & 3) * 16;        // 0,16,32,48
    const int hw  = hw0 + hwl;
    const int i   = hw / HWDIM;
    const int j   = hw % HWDIM;
    short8 o0, o1;
#pragma unroll
    for (int k = 0; k < 8; ++k) {
        o0[k] = (short)f2bf(tile[c0 + k][hwl]);
        o1[k] = (short)f2bf(tile[c0 + 8 + k][hwl]);
    }
    unsigned short* dst = T + ((size_t)(i + 1) * TPAD + (j + 1)) * SLAB + b * 64 + c0;
    *(short8*)dst       = o0;
    *(short8*)(dst + 8) = o1;
}

// ---------------------------------------------------------------------------
// Main kernel: one block per location l. 256 threads = 4 waves.
// Phase 1: gather 9 slabs (contiguous 4KB each) -> LDS sA[b][f] bf16.
// Phase 2: m97-style gemm_bt: W[l,c,f] rows ARE the MFMA B-operand rows
// (B^T layout, k contiguous). Each wave: N-tile = wave id (16 cols),
// both M-tiles (32 rows), K = 576 in 18 steps of 32. W loads non-temporal.
// ---------------------------------------------------------------------------
__global__ __launch_bounds__(256, 4) void lc2d_kernel(
    const unsigned short* __restrict__ T,   // [58][58][32][64] bf16
    const float* __restrict__ W,            // [NLOC][64][576] f32
    const float* __restrict__ bias,         // [NLOC][64] f32
    float* __restrict__ out)                // [32][64][3136] f32
{
    __shared__ unsigned short sA[BATCH][ROWLEN];   // 37,376 B -> 4 blocks/CU

    const int bid = blockIdx.x;
    // XCD-contiguous l ranges: consecutive l share T slabs + out cache lines.
    const int l  = (bid & 7) * (NLOC / 8) + (bid >> 3);
    const int oi = l / HWDIM;
    const int oj = l % HWDIM;
    const int t  = threadIdx.x;

    // ---- Phase 1: patches -> LDS --------------------------------------
    {
        const int b  = t >> 3;           // 0..31
        const int c0 = (t & 7) * 8;      // cin chunk base: 0,8,..,56
        short8 ld[9];
#pragma unroll
        for (int ki = 0; ki < 3; ++ki)
#pragma unroll
            for (int kj = 0; kj < 3; ++kj) {
                const unsigned short* src =
                    T + ((size_t)(oi + ki) * TPAD + (oj + kj)) * SLAB + b * 64 + c0;
                ld[ki * 3 + kj] = *(const short8*)src;
            }
        // repack: f = (c0+ci)*9 + k  -> 72 contiguous bf16 = 9 x b128 stores
        short8 ov[9];
#pragma unroll
        for (int ci = 0; ci < 8; ++ci)
#pragma unroll
            for (int k = 0; k < 9; ++k) {
                const int o = ci * 9 + k;
                ov[o >> 3][o & 7] = ld[k][ci];
            }
        short8* dst = (short8*)&sA[b][c0 * 9];
#pragma unroll
        for (int w = 0; w < 9; ++w) dst[w] = ov[w];
    }
    __syncthreads();

    // ---- Phase 2: stream W (non-temporal), MFMA -----------------------
    const int ln = t & 63;
    const int wv = t >> 6;               // wave id = N-tile
    const int r  = ln & 15;              // row within operand (m or n)
    const int q  = ln >> 4;              // quad: k-offset q*8

    const float* wrow = W + (size_t)l * (COUT * FEAT)
                          + (size_t)(wv * 16 + r) * FEAT + q * 8;
    const unsigned short* a0 = &sA[r][q * 8];        // M-tile 0
    const unsigned short* a1 = &sA[16 + r][q * 8];   // M-tile 1

    f32x4 acc0 = {0.f, 0.f, 0.f, 0.f};
    f32x4 acc1 = {0.f, 0.f, 0.f, 0.f};

    f32x4 w0 = __builtin_nontemporal_load((const f32x4*)(wrow));
    f32x4 w1 = __builtin_nontemporal_load((const f32x4*)(wrow + 4));
#pragma unroll 2
    for (int kk = 0; kk < 18; ++kk) {
        f32x4 nw0, nw1;
        if (kk < 17) {                   // register-rotated prefetch
            nw0 = __builtin_nontemporal_load((const f32x4*)(wrow + (kk + 1) * 32));
            nw1 = __builtin_nontemporal_load((const f32x4*)(wrow + (kk + 1) * 32 + 4));
        }
        short8 bfrag;
        bfrag[0] = (short)f2bf(w0[0]);
        bfrag[1] = (short)f2bf(w0[1]);
        bfrag[2] = (short)f2bf(w0[2]);
        bfrag[3] = (short)f2bf(w0[3]);
        bfrag[4] = (short)f2bf(w1[0]);
        bfrag[5] = (short)f2bf(w1[1]);
        bfrag[6] = (short)f2bf(w1[2]);
        bfrag[7] = (short)f2bf(w1[3]);
        const short8 af0 = *(const short8*)(a0 + kk * 32);
        const short8 af1 = *(const short8*)(a1 + kk * 32);
        acc0 = __builtin_amdgcn_mfma_f32_16x16x32_bf16(af0, bfrag, acc0, 0, 0, 0);
        acc1 = __builtin_amdgcn_mfma_f32_16x16x32_bf16(af1, bfrag, acc1, 0, 0, 0);
        w0 = nw0;
        w1 = nw1;
    }

    // ---- Epilogue: C/D layout col(n=c)=lane&15, row(m=b)=q*4+reg ------
    const int c   = wv * 16 + r;
    const float bv = bias[l * COUT + c];
    float* op = out + (size_t)c * NLOC + l;
#pragma unroll
    for (int i2 = 0; i2 < 4; ++i2) {
        const int b0 = q * 4 + i2;
        op[(size_t)b0 * (COUT * NLOC)]        = acc0[i2] + bv;
        op[(size_t)(b0 + 16) * (COUT * NLOC)] = acc1[i2] + bv;
    }
}

extern "C" void kernel_launch(void* const* d_in, const int* in_sizes, int n_in,
                              void* d_out, int out_size, void* d_ws, size_t ws_size,
                              hipStream_t stream) {
    const float* x    = (const float*)d_in[0];
    const float* w    = (const float*)d_in[1];
    const float* bias = (const float*)d_in[2];
    float* out        = (float*)d_out;

    unsigned short* T = (unsigned short*)d_ws;   // ~13.8 MB of d_ws

    xform_kernel<<<dim3(50, 32), 256, 0, stream>>>(x, T);
    lc2d_kernel<<<dim3(NLOC), 256, 0, stream>>>(T, w, bias, out);
}

// Round 4
// 641.179 us; speedup vs baseline: 1.0140x; 1.0038x over previous
//
#include <hip/hip_runtime.h>

// LocallyConnected2d: B=32, C_IN=64, H=W=56, C_OUT=64, K=3x3, pad=1, stride=1
// out[b,c,l] = sum_f patches[b,l,f] * weight[l,c,f] + bias[l,c]
// f = cin*9 + ki*3 + kj  (channel-major unfold)
//
// Weight (462 MB fp32) is the dominant read-once stream -> HBM-bound floor
// ~75 us. Compute via bf16 MFMA (16x16x32). x is pre-transposed into
// T[58][58][b][cin] bf16 (halo zeroed in-kernel) so the per-location patch
// gather becomes 9 contiguous 4KB slab reads. W loads are non-temporal so the
// 462 MB stream doesn't evict T (re-read 9x) / out lines from L2.
//
// R4: persistent 1024-block grid (4 blocks/CU exactly) grid-striding over l.
// 3136 blocks on 1024 slots had a 64-block final round (~6% util for one
// block-lifetime). Now block k: xcd=k&7, slot=k>>3, l = xcd*392 + t*128 + slot,
// t=0..3 (t=3 only slot<8). Concurrent l-window per XCD is 128 contiguous ->
// T-slab re-reads and out-line merging stay L2-local.

#define BATCH   32
#define CIN     64
#define HWDIM   56
#define COUT    64
#define NLOC    3136
#define FEAT    576
#define TPAD    58
#define SLAB    2048      // 32*64 bf16 elems per (ip,jp)
#define ROWLEN  584       // 576 + 8 pad (16B-aligned rows, breaks pow2 stride)

typedef __attribute__((ext_vector_type(8))) short short8;
typedef __attribute__((ext_vector_type(4))) float f32x4;   // native vec: ok for nontemporal builtins

__device__ __forceinline__ unsigned short f2bf(float f) {
    union { float f; unsigned u; } cv; cv.f = f;
    return (unsigned short)((cv.u + 0x7fffu + ((cv.u >> 16) & 1u)) >> 16);  // RNE
}

// ---------------------------------------------------------------------------
// x [32][64][56][56] f32  ->  T [58][58][32][64] bf16 (zero halo, pad=1)
// grid (50, 32): bx<49 transpose 64 hw-positions; bx==49 zeroes halo slabs.
// ---------------------------------------------------------------------------
__global__ __launch_bounds__(256) void xform_kernel(const float* __restrict__ x,
                                                    unsigned short* __restrict__ T) {
    const int t = threadIdx.x;

    if (blockIdx.x == 49) {
        // zero the 228 halo slabs (rows 0 & 57, cols 0 & 57)
        const short8 z = {0, 0, 0, 0, 0, 0, 0, 0};
        for (int s = blockIdx.y; s < 228; s += 32) {
            int ip, jp;
            if (s < 58)       { ip = 0;        jp = s; }
            else if (s < 116) { ip = 57;       jp = s - 58; }
            else if (s < 172) { ip = s - 115;  jp = 0; }       // rows 1..56
            else              { ip = s - 171;  jp = 57; }      // rows 1..56
            unsigned short* dst = T + ((size_t)ip * TPAD + jp) * SLAB + t * 8;
            *(short8*)dst = z;
        }
        return;
    }

    __shared__ float tile[64][65];       // +1 pad: conflict-free column reads
    const int b   = blockIdx.y;
    const int hw0 = blockIdx.x * 64;     // 3136 = 49 * 64 exactly
    const float* xb = x + (size_t)b * CIN * (HWDIM * HWDIM);

    const int cl = t >> 4;               // 0..15
    const int wl = (t & 15) * 4;         // 0..60
#pragma unroll
    for (int rr = 0; rr < 4; ++rr) {
        const int cin = cl + rr * 16;
        const float4 v = *(const float4*)(xb + (size_t)cin * (HWDIM * HWDIM) + hw0 + wl);
        tile[cin][wl]     = v.x;
        tile[cin][wl + 1] = v.y;
        tile[cin][wl + 2] = v.z;
        tile[cin][wl + 3] = v.w;
    }
    __syncthreads();

    const int hwl = t >> 2;              // 0..63
    const int c0  = (t & 3) * 16;        // 0,16,32,48
    const int hw  = hw0 + hwl;
    const int i   = hw / HWDIM;
    const int j   = hw % HWDIM;
    short8 o0, o1;
#pragma unroll
    for (int k = 0; k < 8; ++k) {
        o0[k] = (short)f2bf(tile[c0 + k][hwl]);
        o1[k] = (short)f2bf(tile[c0 + 8 + k][hwl]);
    }
    unsigned short* dst = T + ((size_t)(i + 1) * TPAD + (j + 1)) * SLAB + b * 64 + c0;
    *(short8*)dst       = o0;
    *(short8*)(dst + 8) = o1;
}

// ---------------------------------------------------------------------------
// Main kernel: persistent, 1024 blocks x 256 threads (4 waves), 4 blocks/CU.
// Per l: Phase 1 gathers 9 contiguous 4KB T slabs -> LDS sA[b][f] bf16;
// Phase 2 streams W (nt), MFMA 16x16x32, each wave owns one 16-col N-tile and
// both 16-row M-tiles, K=576 in 18 steps.
// ---------------------------------------------------------------------------
__global__ __launch_bounds__(256, 4) void lc2d_kernel(
    const unsigned short* __restrict__ T,   // [58][58][32][64] bf16
    const float* __restrict__ W,            // [NLOC][64][576] f32
    const float* __restrict__ bias,         // [NLOC][64] f32
    float* __restrict__ out)                // [32][64][3136] f32
{
    __shared__ unsigned short sA[BATCH][ROWLEN];   // 37,376 B -> 4 blocks/CU

    const int k    = blockIdx.x;         // 0..1023
    const int xcd  = k & 7;
    const int slot = k >> 3;             // 0..127
    const int t    = threadIdx.x;

    // phase-1 constants
    const int p1b  = t >> 3;             // 0..31
    const int p1c0 = (t & 7) * 8;        // cin chunk base
    // phase-2 constants
    const int ln = t & 63;
    const int wv = t >> 6;               // wave id = N-tile
    const int r  = ln & 15;
    const int q  = ln >> 4;
    const unsigned short* a0 = &sA[r][q * 8];
    const unsigned short* a1 = &sA[16 + r][q * 8];

    for (int tt = 0; tt < 4; ++tt) {
        const int off = tt * 128 + slot;
        if (off >= (NLOC / 8)) break;    // 392 per XCD; t=3 only for slot<8
        const int l  = xcd * (NLOC / 8) + off;
        const int oi = l / HWDIM;
        const int oj = l % HWDIM;

        if (tt) __syncthreads();         // sA readers of previous l must finish

        // ---- Phase 1: patches -> LDS ----------------------------------
        {
            short8 ld[9];
#pragma unroll
            for (int ki = 0; ki < 3; ++ki)
#pragma unroll
                for (int kj = 0; kj < 3; ++kj) {
                    const unsigned short* src =
                        T + ((size_t)(oi + ki) * TPAD + (oj + kj)) * SLAB + p1b * 64 + p1c0;
                    ld[ki * 3 + kj] = *(const short8*)src;
                }
            // repack: f = (c0+ci)*9 + kk -> 72 contiguous bf16 = 9 x b128 stores
            short8 ov[9];
#pragma unroll
            for (int ci = 0; ci < 8; ++ci)
#pragma unroll
                for (int kk = 0; kk < 9; ++kk) {
                    const int o = ci * 9 + kk;
                    ov[o >> 3][o & 7] = ld[kk][ci];
                }
            short8* dst = (short8*)&sA[p1b][p1c0 * 9];
#pragma unroll
            for (int w = 0; w < 9; ++w) dst[w] = ov[w];
        }
        __syncthreads();

        // ---- Phase 2: stream W (non-temporal), MFMA -------------------
        const float* wrow = W + (size_t)l * (COUT * FEAT)
                              + (size_t)(wv * 16 + r) * FEAT + q * 8;

        f32x4 acc0 = {0.f, 0.f, 0.f, 0.f};
        f32x4 acc1 = {0.f, 0.f, 0.f, 0.f};

        f32x4 w0 = __builtin_nontemporal_load((const f32x4*)(wrow));
        f32x4 w1 = __builtin_nontemporal_load((const f32x4*)(wrow + 4));
#pragma unroll 2
        for (int kk = 0; kk < 18; ++kk) {
            f32x4 nw0, nw1;
            if (kk < 17) {               // register-rotated prefetch
                nw0 = __builtin_nontemporal_load((const f32x4*)(wrow + (kk + 1) * 32));
                nw1 = __builtin_nontemporal_load((const f32x4*)(wrow + (kk + 1) * 32 + 4));
            }
            short8 bfrag;
            bfrag[0] = (short)f2bf(w0[0]);
            bfrag[1] = (short)f2bf(w0[1]);
            bfrag[2] = (short)f2bf(w0[2]);
            bfrag[3] = (short)f2bf(w0[3]);
            bfrag[4] = (short)f2bf(w1[0]);
            bfrag[5] = (short)f2bf(w1[1]);
            bfrag[6] = (short)f2bf(w1[2]);
            bfrag[7] = (short)f2bf(w1[3]);
            const short8 af0 = *(const short8*)(a0 + kk * 32);
            const short8 af1 = *(const short8*)(a1 + kk * 32);
            acc0 = __builtin_amdgcn_mfma_f32_16x16x32_bf16(af0, bfrag, acc0, 0, 0, 0);
            acc1 = __builtin_amdgcn_mfma_f32_16x16x32_bf16(af1, bfrag, acc1, 0, 0, 0);
            w0 = nw0;
            w1 = nw1;
        }

        // ---- Epilogue: C/D layout col(n=c)=lane&15, row(m=b)=q*4+reg --
        const int c   = wv * 16 + r;
        const float bv = bias[l * COUT + c];
        float* op = out + (size_t)c * NLOC + l;
#pragma unroll
        for (int i2 = 0; i2 < 4; ++i2) {
            const int b0 = q * 4 + i2;
            op[(size_t)b0 * (COUT * NLOC)]        = acc0[i2] + bv;
            op[(size_t)(b0 + 16) * (COUT * NLOC)] = acc1[i2] + bv;
        }
    }
}

extern "C" void kernel_launch(void* const* d_in, const int* in_sizes, int n_in,
                              void* d_out, int out_size, void* d_ws, size_t ws_size,
                              hipStream_t stream) {
    const float* x    = (const float*)d_in[0];
    const float* w    = (const float*)d_in[1];
    const float* bias = (const float*)d_in[2];
    float* out        = (float*)d_out;

    unsigned short* T = (unsigned short*)d_ws;   // ~13.8 MB of d_ws

    xform_kernel<<<dim3(50, 32), 256, 0, stream>>>(x, T);
    lc2d_kernel<<<dim3(1024), 256, 0, stream>>>(T, w, bias, out);
}